// Round 1
// baseline (2200.006 us; speedup 1.0000x reference)
//
#include <hip/hip_runtime.h>
#include <hip/hip_bf16.h>
#include <cmath>

#define BATCH 64
#define SEQ   512
#define ISZ   512
#define HSZ   1024

// Persistent-kernel partition: 64 WGs = 4 batch-groups x 16 col-groups.
// Batch groups are fully independent (h_next[b,:] depends only on h[b,:]),
// so each batch group syncs with its OWN 16-WG barrier.
#define NWG 64
#define BT  16   // batches per WG (one 16-row MFMA m-tile)
#define NT  64   // columns per WG (four 16-col MFMA n-tiles)
#define GRP_WGS 16

typedef __attribute__((ext_vector_type(8))) short short8;   // 8 bf16 (A/B frag)
typedef __attribute__((ext_vector_type(4))) float floatx4;  // C/D frag
typedef unsigned long long ull;

union Frag { short8 s8; ull u2[2]; };

__device__ __forceinline__ ushort f2bf(float f) {
  unsigned u = __builtin_bit_cast(unsigned, f);
  unsigned r = (u + 0x7fffu + ((u >> 16) & 1u)) >> 16;
  return (ushort)r;
}
__device__ __forceinline__ ull pack4(float a, float b, float c, float d) {
  unsigned lo = (unsigned)f2bf(a) | ((unsigned)f2bf(b) << 16);
  unsigned hi = (unsigned)f2bf(c) | ((unsigned)f2bf(d) << 16);
  return (ull)lo | ((ull)hi << 32);
}

// Fast tanh: tanh(x) = (e^{2x} - 1) / (e^{2x} + 1) via v_exp_f32 (2^y) and
// v_rcp_f32. Clamp |x|<=20 keeps e^{2x} finite (no inf/inf). Abs error
// ~1e-6 — far below the tolerance that already absorbs bf16 h/W rounding.
__device__ __forceinline__ float fast_tanh(float x) {
  float cx = fminf(20.f, fmaxf(-20.f, x));
  float e  = __builtin_amdgcn_exp2f(cx * 2.8853900817779268f);  // 2*log2(e)
  return (e - 1.f) * __builtin_amdgcn_rcpf(e + 1.f);
}

// ---------------------------------------------------------------------------
// Kernel 1: x_proj = inputs @ W_xh + b_h  (fp32 tiled GEMM -> d_out, in-place
// with the recurrence: step t reads xp[b,t,:] then overwrites it with h_t)
// ---------------------------------------------------------------------------
__global__ __launch_bounds__(256) void xproj_gemm(
    const float* __restrict__ A,     // (32768, 512)
    const float* __restrict__ Bw,    // (512, 1024)
    const float* __restrict__ bias,  // (1024,)
    float* __restrict__ C) {         // (32768, 1024)
  __shared__ float As[32 * 68];
  __shared__ float Bs[32 * 64];

  const int tid = threadIdx.x;
  const int n0 = blockIdx.x * 64;
  const int m0 = blockIdx.y * 64;
  const int ty = tid >> 4;
  const int tx = tid & 15;

  float acc[4][4] = {};

  for (int kt = 0; kt < ISZ; kt += 32) {
#pragma unroll
    for (int i = 0; i < 8; ++i) {
      int idx = tid + i * 256;
      int m = idx >> 5, k = idx & 31;
      As[k * 68 + m] = A[(size_t)(m0 + m) * ISZ + kt + k];
    }
#pragma unroll
    for (int i = 0; i < 8; ++i) {
      int idx = tid + i * 256;
      int k = idx >> 6, n = idx & 63;
      Bs[k * 64 + n] = Bw[(size_t)(kt + k) * HSZ + n0 + n];
    }
    __syncthreads();

#pragma unroll
    for (int k = 0; k < 32; ++k) {
      const float4 a4 = *(const float4*)(&As[k * 68 + ty * 4]);
      const float4 b4 = *(const float4*)(&Bs[k * 64 + tx * 4]);
      acc[0][0] = fmaf(a4.x, b4.x, acc[0][0]);
      acc[0][1] = fmaf(a4.x, b4.y, acc[0][1]);
      acc[0][2] = fmaf(a4.x, b4.z, acc[0][2]);
      acc[0][3] = fmaf(a4.x, b4.w, acc[0][3]);
      acc[1][0] = fmaf(a4.y, b4.x, acc[1][0]);
      acc[1][1] = fmaf(a4.y, b4.y, acc[1][1]);
      acc[1][2] = fmaf(a4.y, b4.z, acc[1][2]);
      acc[1][3] = fmaf(a4.y, b4.w, acc[1][3]);
      acc[2][0] = fmaf(a4.z, b4.x, acc[2][0]);
      acc[2][1] = fmaf(a4.z, b4.y, acc[2][1]);
      acc[2][2] = fmaf(a4.z, b4.z, acc[2][2]);
      acc[2][3] = fmaf(a4.z, b4.w, acc[2][3]);
      acc[3][0] = fmaf(a4.w, b4.x, acc[3][0]);
      acc[3][1] = fmaf(a4.w, b4.y, acc[3][1]);
      acc[3][2] = fmaf(a4.w, b4.z, acc[3][2]);
      acc[3][3] = fmaf(a4.w, b4.w, acc[3][3]);
    }
    __syncthreads();
  }

  const float4 bv = *(const float4*)(&bias[n0 + tx * 4]);
#pragma unroll
  for (int r = 0; r < 4; ++r) {
    float4 o;
    o.x = acc[r][0] + bv.x;
    o.y = acc[r][1] + bv.y;
    o.z = acc[r][2] + bv.z;
    o.w = acc[r][3] + bv.w;
    *(float4*)(&C[(size_t)(m0 + ty * 4 + r) * HSZ + n0 + tx * 4]) = o;
  }
}

// ---------------------------------------------------------------------------
// Kernel 2: zero the 4 per-group barrier counters (ws is re-poisoned per call)
// ---------------------------------------------------------------------------
__global__ void init_cnt(int* c) { c[threadIdx.x] = 0; }

// ---------------------------------------------------------------------------
// Kernel 3: persistent RNN recurrence. 64 WGs x 256 thr, 1 WG/CU (145 KB LDS).
// All cross-WG traffic (h ping-pong, counters) via RELAXED agent-scope
// atomics (sc1, LLC-coherent) -> NO fences -> no buffer_wbl2/buffer_inv.
// __syncthreads()'s vmcnt(0) drain before the arrive-add = release ordering.
//
// Epilogue order (changed this round): hn store -> release sync -> arrive ->
// out store + xp prefetch (WG-private; overlapped with the spin) -> spin ->
// closing sync. Previously out-store + prefetch sat inside the release drain,
// putting their HBM latency on the inter-WG critical path every step.
// ---------------------------------------------------------------------------
__global__ __launch_bounds__(256, 1) void rnn_persistent(
    const float* __restrict__ h_prev,   // (64, 1024) fp32
    const float* __restrict__ W,        // (1024, 1024) fp32
    float* __restrict__ out,            // (64, 512, 1024) fp32 (xp in, h out)
    ull* __restrict__ h_a,              // (64, 256) bf16x4 ping
    ull* __restrict__ h_b,              // (64, 256) bf16x4 pong
    int* __restrict__ cnt) {            // 4 barrier counters, 256B apart
  extern __shared__ char smem[];
  ushort* Wfrag = (ushort*)smem;                 // 32kc*4nt*64lane*8 = 128 KB
  float*  Cred  = (float*)(smem + 131072);       // 4 waves * 16 * 68 floats

  const int tid = threadIdx.x;
  const int gb = blockIdx.x & 3;       // batch group 0..3
  const int gn = blockIdx.x >> 2;      // col group 0..15
  const int b0 = gb * BT;
  const int n0 = gn * NT;
  int* cnt_g = cnt + gb * 64;          // per-group counter line

  // ---- one-time: W_hh column slice -> bf16 fragments in LDS ----
  for (int it = tid; it < 1024 * 16; it += 256) {
    int k  = it >> 4;
    int c4 = (it & 15) << 2;
    float4 w4 = *(const float4*)&W[(size_t)k * HSZ + n0 + c4];
    int kc = k >> 5, j = k & 7, q = (k >> 3) & 3;
    float wv[4] = {w4.x, w4.y, w4.z, w4.w};
#pragma unroll
    for (int e = 0; e < 4; ++e) {
      int n = c4 + e;
      int nt = n >> 4;
      int lane = q * 16 + (n & 15);
      Wfrag[((kc * 4 + nt) * 64 + lane) * 8 + j] = f2bf(wv[e]);
    }
  }

  // ---- one-time: h0 = bf16(h_prev), written by the 4 gn==0 WGs (sc1) ----
  if (gn == 0) {
    for (int it = tid; it < BT * 256; it += 256) {
      int r = it >> 8;
      int c4 = (it & 255) << 2;
      float4 v = *(const float4*)&h_prev[(size_t)(b0 + r) * HSZ + c4];
      __hip_atomic_store(&h_a[(size_t)(b0 + r) * 256 + (c4 >> 2)],
                         pack4(v.x, v.y, v.z, v.w),
                         __ATOMIC_RELAXED, __HIP_MEMORY_SCOPE_AGENT);
    }
  }

  const int w  = tid >> 6;             // wave 0..3 -> K quarter
  const int l  = tid & 63;
  const int bRow = b0 + (l & 15);      // A-frag row (batch)
  const int q2 = ((l >> 4) & 3) * 2;   // frag k sub-offset in 8B units

  // epilogue mapping (also used for xp prefetch)
  const int eb  = tid >> 4;            // 0..15 batch row
  const int en4 = (tid & 15) << 2;     // col*4
  const size_t obase = ((size_t)(b0 + eb) * SEQ) * HSZ + n0 + en4;

  ull* hc = h_a;
  ull* hn = h_b;

  // prefetch xp for t=0 (no dependency on h)
  float4 xp = *(const float4*)&out[obase];

  int target = GRP_WGS;

  // ---- barrier: h0 ready ----
  __syncthreads();   // drains vmcnt(0): h0 sc1 stores globally visible
  if (tid == 0) {
    __hip_atomic_fetch_add(cnt_g, 1, __ATOMIC_RELAXED,
                           __HIP_MEMORY_SCOPE_AGENT);
    while (__hip_atomic_load(cnt_g, __ATOMIC_RELAXED,
                             __HIP_MEMORY_SCOPE_AGENT) < target)
      __builtin_amdgcn_s_sleep(1);
  }
  __syncthreads();
  target += GRP_WGS;

  for (int t = 0; t < SEQ; ++t) {
    // ---- load this wave's 8 A-frags (sc1, pipelined 8B loads) ----
    Frag af[8];
    const ull* hq = hc + (size_t)bRow * 256;
#pragma unroll
    for (int i = 0; i < 8; ++i) {
      const int off = (w * 8 + i) * 8 + q2;
      af[i].u2[0] = __hip_atomic_load(hq + off, __ATOMIC_RELAXED,
                                      __HIP_MEMORY_SCOPE_AGENT);
      af[i].u2[1] = __hip_atomic_load(hq + off + 1, __ATOMIC_RELAXED,
                                      __HIP_MEMORY_SCOPE_AGENT);
    }

    floatx4 acc[4] = {floatx4{0.f, 0.f, 0.f, 0.f}, floatx4{0.f, 0.f, 0.f, 0.f},
                      floatx4{0.f, 0.f, 0.f, 0.f}, floatx4{0.f, 0.f, 0.f, 0.f}};
#pragma unroll
    for (int i = 0; i < 8; ++i) {
      const int kc = w * 8 + i;
#pragma unroll
      for (int nt = 0; nt < 4; ++nt) {
        short8 b8 = *(const short8*)&Wfrag[((kc * 4 + nt) * 64 + l) * 8];
        acc[nt] = __builtin_amdgcn_mfma_f32_16x16x32_bf16(af[i].s8, b8, acc[nt], 0, 0, 0);
      }
    }

    // partial C tiles -> LDS (C/D layout: col=lane&15, row=(lane>>4)*4+reg)
    {
      const int rbase = (l >> 4) * 4;
      const int cbase = l & 15;
#pragma unroll
      for (int nt = 0; nt < 4; ++nt)
#pragma unroll
        for (int r = 0; r < 4; ++r)
          Cred[(w * 16 + rbase + r) * 68 + nt * 16 + cbase] = acc[nt][r];
    }
    __syncthreads();

    // reduce 4 wave partials, tanh, publish hn (release-critical part ONLY)
    float4 hv;
    {
      float4 v0 = *(const float4*)&Cred[(0 * 16 + eb) * 68 + en4];
      float4 v1 = *(const float4*)&Cred[(1 * 16 + eb) * 68 + en4];
      float4 v2 = *(const float4*)&Cred[(2 * 16 + eb) * 68 + en4];
      float4 v3 = *(const float4*)&Cred[(3 * 16 + eb) * 68 + en4];
      hv.x = fast_tanh(v0.x + v1.x + v2.x + v3.x + xp.x);
      hv.y = fast_tanh(v0.y + v1.y + v2.y + v3.y + xp.y);
      hv.z = fast_tanh(v0.z + v1.z + v2.z + v3.z + xp.z);
      hv.w = fast_tanh(v0.w + v1.w + v2.w + v3.w + xp.w);
      __hip_atomic_store(&hn[((size_t)(b0 + eb) * 256) + ((n0 + en4) >> 2)],
                         pack4(hv.x, hv.y, hv.z, hv.w),
                         __ATOMIC_RELAXED, __HIP_MEMORY_SCOPE_AGENT);
    }

    // release: drains ONLY the hn sc1 stores (out store / prefetch from the
    // previous step completed long ago) -> minimal pre-arrive latency.
    __syncthreads();
    if (tid == 0)
      __hip_atomic_fetch_add(cnt_g, 1, __ATOMIC_RELAXED,
                             __HIP_MEMORY_SCOPE_AGENT);

    // WG-private work, overlapped with peers' arrival and our own spin:
    *(float4*)&out[obase + (size_t)t * HSZ] = hv;          // h_t -> out (HBM)
    if (t + 1 < SEQ)                                       // next xp prefetch
      xp = *(const float4*)&out[obase + (size_t)(t + 1) * HSZ];

    if (tid == 0) {
      while (__hip_atomic_load(cnt_g, __ATOMIC_RELAXED,
                               __HIP_MEMORY_SCOPE_AGENT) < target)
        __builtin_amdgcn_s_sleep(1);
    }
    __syncthreads();
    target += GRP_WGS;

    ull* tmp = hc; hc = hn; hn = tmp;
  }
}

// ---------------------------------------------------------------------------
extern "C" void kernel_launch(void* const* d_in, const int* in_sizes, int n_in,
                              void* d_out, int out_size, void* d_ws, size_t ws_size,
                              hipStream_t stream) {
  const float* inputs = (const float*)d_in[0];  // (64, 512, 512)
  const float* h_prev = (const float*)d_in[1];  // (64, 1024)
  const float* W_xh   = (const float*)d_in[2];  // (512, 1024)
  const float* W_hh   = (const float*)d_in[3];  // (1024, 1024)
  const float* b_h    = (const float*)d_in[4];  // (1024,)
  float* out = (float*)d_out;                   // (64, 512, 1024)

  int* cnt = (int*)d_ws;                        // 4 counters, 256B apart
  ull* h_a = (ull*)((char*)d_ws + 1024);
  ull* h_b = h_a + BATCH * 256;                 // 128 KB each

  // 1. x_proj -> d_out
  dim3 g1(HSZ / 64, (BATCH * SEQ) / 64);        // (16, 512)
  xproj_gemm<<<g1, 256, 0, stream>>>(inputs, W_xh, b_h, out);

  // 2. zero barrier counters
  init_cnt<<<1, 256, 0, stream>>>(cnt);

  // 3. persistent recurrence (145 KB dynamic LDS -> 1 WG/CU)
  const int smem_bytes = 131072 + 4 * 16 * 68 * (int)sizeof(float);  // 148480
  hipFuncSetAttribute((const void*)rnn_persistent,
                      hipFuncAttributeMaxDynamicSharedMemorySize, smem_bytes);
  rnn_persistent<<<NWG, 256, smem_bytes, stream>>>(h_prev, W_hh, out, h_a, h_b, cnt);
}

// Round 3
// 2131.430 us; speedup vs baseline: 1.0322x; 1.0322x over previous
//
#include <hip/hip_runtime.h>
#include <hip/hip_bf16.h>
#include <cmath>

#define BATCH 64
#define SEQ   512
#define ISZ   512
#define HSZ   1024

// Persistent-kernel partition: 64 WGs = 4 batch-groups x 16 col-groups.
// Batch groups are fully independent (h_next[b,:] depends only on h[b,:]).
// Sync: per-producer step FLAGS (parallel stores — no RMW chain), but the
// PROVEN consumer ordering from the passing round-1 kernel is retained:
// observation (wave 0, lanes 0..15 scan all 16 group flags) -> closing
// __syncthreads broadcast -> h loads. Round-2's per-wave early-start (loads
// issued lanes-cycles after flag observation, gated on only 4 flags) raced;
// that mechanism is reverted.
#define NWG 64
#define BT  16   // batches per WG (one 16-row MFMA m-tile)
#define NT  64   // columns per WG (four 16-col MFMA n-tiles)
#define GRP_WGS 16
#define FLAG_STRIDE 32   // ints: 128B line spacing per flag

typedef __attribute__((ext_vector_type(8))) short short8;   // 8 bf16 (A/B frag)
typedef __attribute__((ext_vector_type(4))) float floatx4;  // C/D frag
typedef unsigned long long ull;

union Frag { short8 s8; ull u2[2]; };

__device__ __forceinline__ ushort f2bf(float f) {
  unsigned u = __builtin_bit_cast(unsigned, f);
  unsigned r = (u + 0x7fffu + ((u >> 16) & 1u)) >> 16;
  return (ushort)r;
}
__device__ __forceinline__ ull pack4(float a, float b, float c, float d) {
  unsigned lo = (unsigned)f2bf(a) | ((unsigned)f2bf(b) << 16);
  unsigned hi = (unsigned)f2bf(c) | ((unsigned)f2bf(d) << 16);
  return (ull)lo | ((ull)hi << 32);
}

// Fast tanh via v_exp_f32/v_rcp_f32; |err| ~1e-6, clamp keeps it NaN-safe.
// (Present in the round-1 PASSING run, absmax 0.0039.)
__device__ __forceinline__ float fast_tanh(float x) {
  float cx = fminf(20.f, fmaxf(-20.f, x));
  float e  = __builtin_amdgcn_exp2f(cx * 2.8853900817779268f);  // 2*log2(e)
  return (e - 1.f) * __builtin_amdgcn_rcpf(e + 1.f);
}

// ---------------------------------------------------------------------------
// Kernel 1: x_proj = inputs @ W_xh + b_h  (fp32, 128x128 tile, 8x8 acc/thread
// -> 64 FMA per 4 LDS b128 reads = FMA-issue-bound, vs 16:2 in the old 64x64)
// ---------------------------------------------------------------------------
__global__ __launch_bounds__(256) void xproj_gemm(
    const float* __restrict__ A,     // (32768, 512) row-major
    const float* __restrict__ Bw,    // (512, 1024) row-major
    const float* __restrict__ bias,  // (1024,)
    float* __restrict__ C) {         // (32768, 1024)
  __shared__ float As[16][132];      // [k][m], padded (132*4B % 16 == 0)
  __shared__ float Bs[16][128];      // [k][n]

  const int tid = threadIdx.x;
  const int n0 = blockIdx.x * 128;
  const int m0 = blockIdx.y * 128;
  const int ty = (tid >> 4) & 15;    // 0..15
  const int tx = tid & 15;           // 0..15

  float acc[8][8] = {};

  // staging maps
  const int ar = tid >> 2;           // 0..63  A row within half-tile
  const int ak = (tid & 3) << 2;     // 0,4,8,12
  const int bk = tid >> 5;           // 0..7   B k within half
  const int bn = (tid & 31) << 2;    // 0..124

  for (int kt = 0; kt < ISZ; kt += 16) {
    __syncthreads();
#pragma unroll
    for (int h = 0; h < 2; ++h) {
      int row = ar + h * 64;
      float4 v = *(const float4*)&A[(size_t)(m0 + row) * ISZ + kt + ak];
      As[ak + 0][row] = v.x;
      As[ak + 1][row] = v.y;
      As[ak + 2][row] = v.z;
      As[ak + 3][row] = v.w;
    }
#pragma unroll
    for (int h = 0; h < 2; ++h) {
      int k = bk + h * 8;
      float4 v = *(const float4*)&Bw[(size_t)(kt + k) * HSZ + n0 + bn];
      *(float4*)&Bs[k][bn] = v;
    }
    __syncthreads();

#pragma unroll
    for (int k = 0; k < 16; ++k) {
      const float4* Ar4 = (const float4*)&As[k][0];
      const float4* Br4 = (const float4*)&Bs[k][0];
      float4 a0 = Ar4[ty];       // rows ty*4..ty*4+3
      float4 a1 = Ar4[16 + ty];  // rows 64+ty*4..
      float4 b0 = Br4[tx];       // cols tx*4..
      float4 b1 = Br4[16 + tx];  // cols 64+tx*4..
      float av[8] = {a0.x, a0.y, a0.z, a0.w, a1.x, a1.y, a1.z, a1.w};
      float bv[8] = {b0.x, b0.y, b0.z, b0.w, b1.x, b1.y, b1.z, b1.w};
#pragma unroll
      for (int i = 0; i < 8; ++i)
#pragma unroll
        for (int j = 0; j < 8; ++j)
          acc[i][j] = fmaf(av[i], bv[j], acc[i][j]);
    }
  }

  const float4 bv0 = *(const float4*)&bias[n0 + tx * 4];
  const float4 bv1 = *(const float4*)&bias[n0 + 64 + tx * 4];
#pragma unroll
  for (int i = 0; i < 8; ++i) {
    int row = m0 + ((i < 4) ? (ty * 4 + i) : (64 + ty * 4 + (i - 4)));
    float4 o0, o1;
    o0.x = acc[i][0] + bv0.x;  o0.y = acc[i][1] + bv0.y;
    o0.z = acc[i][2] + bv0.z;  o0.w = acc[i][3] + bv0.w;
    o1.x = acc[i][4] + bv1.x;  o1.y = acc[i][5] + bv1.y;
    o1.z = acc[i][6] + bv1.z;  o1.w = acc[i][7] + bv1.w;
    *(float4*)&C[(size_t)row * HSZ + n0 + tx * 4] = o0;
    *(float4*)&C[(size_t)row * HSZ + n0 + 64 + tx * 4] = o1;
  }
}

// ---------------------------------------------------------------------------
// Kernel 2: init the 64 per-producer step flags to -1 ("nothing published")
// (ws is re-poisoned per call, so this runs every launch)
// ---------------------------------------------------------------------------
__global__ void init_cnt(int* c) { c[threadIdx.x * FLAG_STRIDE] = -1; }

// ---------------------------------------------------------------------------
// Kernel 3: persistent RNN recurrence. 64 WGs x 256 thr, 1 WG/CU (145 KB LDS).
// Per step t (flag[p] == s  <=>  producer p's h_s drained to LLC):
//   wave 0, lanes 0..15: spin until ALL 16 group flags >= t
//   __syncthreads()                 <- closing broadcast (proven ordering:
//                                      observation -> barrier -> loads)
//   load h_t frags (sc1) -> MFMA -> Cred -> sync1
//   reduce + tanh -> store hn slice (sc1) -> sync2 (vmcnt0 drain = release)
//   tid0: flag[self] = t+1          <- parallel store, no RMW chain
//   out store + xp prefetch (WG-private, off the critical path)
// Overwrite safety: before any thread of WG X stores h_{t+1} into buf A
// (holding h_{t-1}), X's closing barrier completed with all 16 flags >= t,
// i.e. every WG passed its step-(t-1)... specifically flag[Y] >= t means Y
// finished step t-1 (sync2 drained its loads of A). Two buffers suffice.
// ---------------------------------------------------------------------------
__global__ __launch_bounds__(256, 1) void rnn_persistent(
    const float* __restrict__ h_prev,   // (64, 1024) fp32
    const float* __restrict__ W,        // (1024, 1024) fp32
    float* __restrict__ out,            // (64, 512, 1024) fp32 (xp in, h out)
    ull* __restrict__ h_a,              // (64, 256) bf16x4 ping
    ull* __restrict__ h_b,              // (64, 256) bf16x4 pong
    int* __restrict__ cnt) {            // 64 step flags, 128B apart
  extern __shared__ char smem[];
  ushort* Wfrag = (ushort*)smem;                 // 32kc*4nt*64lane*8 = 128 KB
  float*  Cred  = (float*)(smem + 131072);       // 4 waves * 16 * 68 floats

  const int tid = threadIdx.x;
  const int gb = blockIdx.x & 3;       // batch group 0..3
  const int gn = blockIdx.x >> 2;      // col group 0..15
  const int b0 = gb * BT;
  const int n0 = gn * NT;
  int* myFlag = cnt + (gb * GRP_WGS + gn) * FLAG_STRIDE;

  // ---- one-time: W_hh column slice -> bf16 fragments in LDS ----
  for (int it = tid; it < 1024 * 16; it += 256) {
    int k  = it >> 4;
    int c4 = (it & 15) << 2;
    float4 w4 = *(const float4*)&W[(size_t)k * HSZ + n0 + c4];
    int kc = k >> 5, j = k & 7, q = (k >> 3) & 3;
    float wv[4] = {w4.x, w4.y, w4.z, w4.w};
#pragma unroll
    for (int e = 0; e < 4; ++e) {
      int n = c4 + e;
      int nt = n >> 4;
      int lane = q * 16 + (n & 15);
      Wfrag[((kc * 4 + nt) * 64 + lane) * 8 + j] = f2bf(wv[e]);
    }
  }

  // ---- one-time: OWN slice of h0 = bf16(h_prev) -> h_a (sc1) ----
  {
    int r  = tid >> 4;                 // 0..15 row
    int c  = tid & 15;                 // 0..15 ull col within slice
    int col4 = n0 + c * 4;
    float4 v = *(const float4*)&h_prev[(size_t)(b0 + r) * HSZ + col4];
    __hip_atomic_store(&h_a[(size_t)(b0 + r) * 256 + (col4 >> 2)],
                       pack4(v.x, v.y, v.z, v.w),
                       __ATOMIC_RELAXED, __HIP_MEMORY_SCOPE_AGENT);
  }

  const int w  = tid >> 6;             // wave 0..3 -> K quarter
  const int l  = tid & 63;
  const int bRow = b0 + (l & 15);      // A-frag row (batch)
  const int q2 = ((l >> 4) & 3) * 2;   // frag k sub-offset in 8B units

  // wave 0's flag-scan pointer: lane i (0..15) polls group flag i
  int* scanFlag = cnt + (gb * GRP_WGS + (l & 15)) * FLAG_STRIDE;

  // epilogue mapping (also used for xp prefetch)
  const int eb  = tid >> 4;            // 0..15 batch row
  const int en4 = (tid & 15) << 2;     // col*4
  const size_t obase = ((size_t)(b0 + eb) * SEQ) * HSZ + n0 + en4;

  ull* hc = h_a;
  ull* hn = h_b;

  // prefetch xp for t=0 (no dependency on h)
  float4 xp = *(const float4*)&out[obase];

  // publish h0: __syncthreads drains the h0 slice stores (vmcnt0), then flag
  __syncthreads();
  if (tid == 0)
    __hip_atomic_store(myFlag, 0, __ATOMIC_RELAXED, __HIP_MEMORY_SCOPE_AGENT);

  for (int t = 0; t < SEQ; ++t) {
    // ---- acquire: wave 0 scans all 16 group flags (one per lane) ----
    if (w == 0) {
      while (__hip_atomic_load(scanFlag, __ATOMIC_RELAXED,
                               __HIP_MEMORY_SCOPE_AGENT) < t)
        __builtin_amdgcn_s_sleep(1);
    }
    __syncthreads();   // closing broadcast: no h load precedes observation

    // ---- load this wave's 8 A-frags (sc1, pipelined 8B loads) ----
    Frag af[8];
    const ull* hq = hc + (size_t)bRow * 256;
#pragma unroll
    for (int i = 0; i < 8; ++i) {
      const int off = (w * 8 + i) * 8 + q2;
      af[i].u2[0] = __hip_atomic_load(hq + off, __ATOMIC_RELAXED,
                                      __HIP_MEMORY_SCOPE_AGENT);
      af[i].u2[1] = __hip_atomic_load(hq + off + 1, __ATOMIC_RELAXED,
                                      __HIP_MEMORY_SCOPE_AGENT);
    }

    floatx4 acc[4] = {floatx4{0.f, 0.f, 0.f, 0.f}, floatx4{0.f, 0.f, 0.f, 0.f},
                      floatx4{0.f, 0.f, 0.f, 0.f}, floatx4{0.f, 0.f, 0.f, 0.f}};
#pragma unroll
    for (int i = 0; i < 8; ++i) {
      const int kc = w * 8 + i;
#pragma unroll
      for (int nt = 0; nt < 4; ++nt) {
        short8 b8 = *(const short8*)&Wfrag[((kc * 4 + nt) * 64 + l) * 8];
        acc[nt] = __builtin_amdgcn_mfma_f32_16x16x32_bf16(af[i].s8, b8, acc[nt], 0, 0, 0);
      }
    }

    // partial C tiles -> LDS (C/D layout: col=lane&15, row=(lane>>4)*4+reg)
    {
      const int rbase = (l >> 4) * 4;
      const int cbase = l & 15;
#pragma unroll
      for (int nt = 0; nt < 4; ++nt)
#pragma unroll
        for (int r = 0; r < 4; ++r)
          Cred[(w * 16 + rbase + r) * 68 + nt * 16 + cbase] = acc[nt][r];
    }
    __syncthreads();   // sync1

    // reduce 4 wave partials, tanh, publish hn slice
    float4 hv;
    {
      float4 v0 = *(const float4*)&Cred[(0 * 16 + eb) * 68 + en4];
      float4 v1 = *(const float4*)&Cred[(1 * 16 + eb) * 68 + en4];
      float4 v2 = *(const float4*)&Cred[(2 * 16 + eb) * 68 + en4];
      float4 v3 = *(const float4*)&Cred[(3 * 16 + eb) * 68 + en4];
      hv.x = fast_tanh(v0.x + v1.x + v2.x + v3.x + xp.x);
      hv.y = fast_tanh(v0.y + v1.y + v2.y + v3.y + xp.y);
      hv.z = fast_tanh(v0.z + v1.z + v2.z + v3.z + xp.z);
      hv.w = fast_tanh(v0.w + v1.w + v2.w + v3.w + xp.w);
      __hip_atomic_store(&hn[((size_t)(b0 + eb) * 256) + ((n0 + en4) >> 2)],
                         pack4(hv.x, hv.y, hv.z, hv.w),
                         __ATOMIC_RELAXED, __HIP_MEMORY_SCOPE_AGENT);
    }

    // sync2: (a) separates Cred read from next step's Cred write,
    // (b) release — every thread's hn store drained (vmcnt0) before the
    // flag store below. Same mechanism as the passing round-0/1 versions.
    __syncthreads();
    if (tid == 0)
      __hip_atomic_store(myFlag, t + 1, __ATOMIC_RELAXED,
                         __HIP_MEMORY_SCOPE_AGENT);

    // WG-private work, off the inter-WG critical path:
    *(float4*)&out[obase + (size_t)t * HSZ] = hv;          // h_t -> out (HBM)
    if (t + 1 < SEQ)                                       // next xp prefetch
      xp = *(const float4*)&out[obase + (size_t)(t + 1) * HSZ];

    ull* tmp = hc; hc = hn; hn = tmp;
  }
}

// ---------------------------------------------------------------------------
extern "C" void kernel_launch(void* const* d_in, const int* in_sizes, int n_in,
                              void* d_out, int out_size, void* d_ws, size_t ws_size,
                              hipStream_t stream) {
  const float* inputs = (const float*)d_in[0];  // (64, 512, 512)
  const float* h_prev = (const float*)d_in[1];  // (64, 1024)
  const float* W_xh   = (const float*)d_in[2];  // (512, 1024)
  const float* W_hh   = (const float*)d_in[3];  // (1024, 1024)
  const float* b_h    = (const float*)d_in[4];  // (1024,)
  float* out = (float*)d_out;                   // (64, 512, 1024)

  int* cnt = (int*)d_ws;                        // 64 flags, 128B apart (8 KB)
  ull* h_a = (ull*)((char*)d_ws + 8192);
  ull* h_b = h_a + BATCH * 256;                 // 128 KB each

  // 1. x_proj -> d_out
  dim3 g1(HSZ / 128, (BATCH * SEQ) / 128);      // (8, 256)
  xproj_gemm<<<g1, 256, 0, stream>>>(inputs, W_xh, b_h, out);

  // 2. init per-producer flags to -1
  init_cnt<<<1, 64, 0, stream>>>(cnt);

  // 3. persistent recurrence (145 KB dynamic LDS -> 1 WG/CU)
  const int smem_bytes = 131072 + 4 * 16 * 68 * (int)sizeof(float);  // 148480
  hipFuncSetAttribute((const void*)rnn_persistent,
                      hipFuncAttributeMaxDynamicSharedMemorySize, smem_bytes);
  rnn_persistent<<<NWG, 256, smem_bytes, stream>>>(h_prev, W_hh, out, h_a, h_b, cnt);
}